// Round 5
// baseline (519.694 us; speedup 1.0000x reference)
//
#include <hip/hip_runtime.h>

#define N_USERS 40000
#define N_ITEMS 60000
#define N_TOTAL 100000
#define M_PAD   100032   // rows padded to multiple of 64
#define NEDGES  600000
#define IN_DIM  128
#define HID     256

typedef short  bf16x8 __attribute__((ext_vector_type(8)));
typedef float  f32x4  __attribute__((ext_vector_type(4)));
typedef unsigned short ushort4v __attribute__((ext_vector_type(4)));
typedef unsigned short ushort8v __attribute__((ext_vector_type(8)));

__device__ __forceinline__ unsigned short f2bf(float f) {   // RNE fp32->bf16
    unsigned u = __builtin_bit_cast(unsigned, f);
    unsigned r = (u + 0x7FFFu + ((u >> 16) & 1u)) >> 16;
    return (unsigned short)r;
}
__device__ __forceinline__ float bf2f(unsigned short b) {
    unsigned u = ((unsigned)b) << 16;
    return __builtin_bit_cast(float, u);
}

__device__ __forceinline__ void gload_lds16(const void* g, void* l) {
    __builtin_amdgcn_global_load_lds(
        (const __attribute__((address_space(1))) unsigned int*)g,
        (__attribute__((address_space(3))) unsigned int*)l, 16, 0, 0);
}

// ---------------------------------------------------------------------------
// Prep: feats fp32 -> bf16 (concat user+item)
// ---------------------------------------------------------------------------
__global__ __launch_bounds__(256) void prep_feats(const float* __restrict__ uf,
                                                  const float* __restrict__ itf,
                                                  unsigned short* __restrict__ outp) {
    const long i8 = (long)(blockIdx.x * 256 + threadIdx.x) * 8;
    if (i8 >= (long)N_TOTAL * IN_DIM) return;
    const long uend = (long)N_USERS * IN_DIM;
    const float4* src = (i8 < uend) ? (const float4*)(uf + i8)
                                    : (const float4*)(itf + (i8 - uend));
    float4 a = src[0], b = src[1];
    ushort8v o;
    o[0] = f2bf(a.x); o[1] = f2bf(a.y); o[2] = f2bf(a.z); o[3] = f2bf(a.w);
    o[4] = f2bf(b.x); o[5] = f2bf(b.y); o[6] = f2bf(b.z); o[7] = f2bf(b.w);
    *(ushort8v*)(outp + i8) = o;
}

// ---------------------------------------------------------------------------
// Prep: weights -> transposed bf16. Wcat_t[512][128] = [W0 | Wres0]^T,
// W1_t[256][256] = W1^T.
// ---------------------------------------------------------------------------
__global__ __launch_bounds__(256) void prep_weights(const float* __restrict__ W0,
                                                    const float* __restrict__ Wres0,
                                                    const float* __restrict__ W1,
                                                    unsigned short* __restrict__ Wcat_t,
                                                    unsigned short* __restrict__ W1_t) {
    const int id = blockIdx.x * 256 + threadIdx.x;
    if (id < 512 * IN_DIM) {
        const int n = id >> 7, k = id & 127;
        const float v = (n < HID) ? W0[(size_t)k * HID + n]
                                  : Wres0[(size_t)k * HID + (n - HID)];
        Wcat_t[id] = f2bf(v);
    } else {
        const int id2 = id - 512 * IN_DIM;
        const int n = id2 >> 8, k = id2 & 255;
        W1_t[id2] = f2bf(W1[(size_t)k * HID + n]);
    }
}

// ---------------------------------------------------------------------------
// MFMA GEMM v3: C[M, gy*256..gy*256+255] = A[M,K] @ Bt[gy*256+n][K]^T.
// Block: 64 rows x 256 cols, 4 waves in 2x2 (wave tile 32x128).
// A panel staged ONCE to LDS (XOR-swizzled source, linear dest), ONE barrier.
// B fragments read DIRECTLY from global (L2-resident weights, <=256KB) — no
// per-K-step barriers, so the compiler pipelines B loads across K-steps.
// EPI=0: out0 = acc + bias.  EPI=1: gy==0 -> out0=acc+bias (x); gy==1 -> out1=acc.
// ---------------------------------------------------------------------------
template <int K, int EPI>
__global__ __launch_bounds__(256) void mfma_gemm3(const unsigned short* __restrict__ A,
                                                  const unsigned short* __restrict__ Bt,
                                                  const float* __restrict__ bias,
                                                  unsigned short* __restrict__ out0,
                                                  unsigned short* __restrict__ out1) {
    constexpr int NK    = K / 32;
    constexpr int SHIFT = (K == 256) ? 9 : 8;       // log2(As row bytes)
    __shared__ unsigned short As[64 * K];

    const int t  = threadIdx.x;
    const int w  = t >> 6, l = t & 63;
    const int fr = l & 15, fb = l >> 4;
    const int wr = w >> 1, wc = w & 1;              // 2x2 wave grid
    const int m0 = blockIdx.x * 64;
    const int gy = blockIdx.y;                      // 256-col group

    // ---- stage As (64 x K, contiguous panel); source pre-swizzled ----
    const char* Ag = (const char*)(A + (size_t)m0 * K);
    constexpr int ACALLS = (64 * K * 2) / (16 * 256);
    #pragma unroll
    for (int i = 0; i < ACALLS; ++i) {
        const int L = (i * 256 + t) * 16;                 // linear LDS byte
        const int U = L ^ (((L >> SHIFT) & 7) << 4);      // global source byte
        gload_lds16(Ag + U, (char*)As + L);
    }
    __syncthreads();   // drains vmcnt for the LDS-stage; the ONLY barrier

    const unsigned short* Bg = Bt + ((size_t)gy * 256 + wc * 128) * K;

    f32x4 acc[2][8] = {};
    for (int kt = 0; kt < NK; ++kt) {
        const char* as_base = (const char*)As;
        bf16x8 af[2];
        #pragma unroll
        for (int rb = 0; rb < 2; ++rb) {
            const int row = wr * 32 + rb * 16 + fr;
            const int Sa = ((row * K + kt * 32 + fb * 8) * 2) ^ ((fr & 7) << 4);
            af[rb] = *(const bf16x8*)(as_base + Sa);
        }
        #pragma unroll
        for (int nt = 0; nt < 8; ++nt) {
            const bf16x8 bfr = *(const bf16x8*)(Bg + (size_t)(nt * 16 + fr) * K + kt * 32 + fb * 8);
            acc[0][nt] = __builtin_amdgcn_mfma_f32_16x16x32_bf16(af[0], bfr, acc[0][nt], 0, 0, 0);
            acc[1][nt] = __builtin_amdgcn_mfma_f32_16x16x32_bf16(af[1], bfr, acc[1][nt], 0, 0, 0);
        }
    }

    // ---- epilogue ----
    const bool use1 = (EPI == 1) && (gy == 1);
    unsigned short* outp = use1 ? out1 : out0;
    #pragma unroll
    for (int rb = 0; rb < 2; ++rb) {
        #pragma unroll
        for (int nt = 0; nt < 8; ++nt) {
            const int col = wc * 128 + nt * 16 + fr;
            const float bv = use1 ? 0.f : bias[col];
            #pragma unroll
            for (int j = 0; j < 4; ++j) {
                const int row = m0 + wr * 32 + rb * 16 + fb * 4 + j;
                if (row < N_TOTAL)
                    outp[(size_t)row * HID + col] = f2bf(acc[rb][nt][j] + bv);
            }
        }
    }
}

// ---------------------------------------------------------------------------
// CSR build: histogram -> exclusive scan -> fill (col,val packed as int2)
// ---------------------------------------------------------------------------
__global__ __launch_bounds__(256) void edge_histogram(const int* __restrict__ rows,
                                                      int* __restrict__ cnt) {
    int e = blockIdx.x * 256 + threadIdx.x;
    if (e < NEDGES) atomicAdd(&cnt[rows[e]], 1);
}

#define SCAN_B 1024
__global__ __launch_bounds__(SCAN_B) void scan_blocks(const int* __restrict__ cnt,
                                                      int* __restrict__ row_ptr,
                                                      int* __restrict__ bsums) {
    __shared__ int s[SCAN_B];
    const int gid = blockIdx.x * SCAN_B + threadIdx.x;
    const int v = (gid < N_TOTAL) ? cnt[gid] : 0;
    s[threadIdx.x] = v;
    __syncthreads();
    for (int off = 1; off < SCAN_B; off <<= 1) {
        int tv = (threadIdx.x >= off) ? s[threadIdx.x - off] : 0;
        __syncthreads();
        s[threadIdx.x] += tv;
        __syncthreads();
    }
    if (gid < N_TOTAL) row_ptr[gid] = s[threadIdx.x] - v;
    if (threadIdx.x == SCAN_B - 1) bsums[blockIdx.x] = s[threadIdx.x];
}

__global__ __launch_bounds__(128) void scan_sums(int* __restrict__ bsums, int nb) {
    __shared__ int s[128];
    const int v = (threadIdx.x < nb) ? bsums[threadIdx.x] : 0;
    s[threadIdx.x] = v;
    __syncthreads();
    for (int off = 1; off < 128; off <<= 1) {
        int tv = (threadIdx.x >= off) ? s[threadIdx.x - off] : 0;
        __syncthreads();
        s[threadIdx.x] += tv;
        __syncthreads();
    }
    if (threadIdx.x < nb) bsums[threadIdx.x] = s[threadIdx.x] - v;
}

__global__ __launch_bounds__(SCAN_B) void scan_apply(int* __restrict__ row_ptr,
                                                     const int* __restrict__ bsums,
                                                     int* __restrict__ next) {
    const int gid = blockIdx.x * SCAN_B + threadIdx.x;
    if (gid < N_TOTAL) {
        const int p = row_ptr[gid] + bsums[blockIdx.x];
        row_ptr[gid] = p;
        next[gid] = p;
    }
    if (gid == 0) row_ptr[N_TOTAL] = NEDGES;
}

__global__ __launch_bounds__(256) void csr_fill(const int* __restrict__ rows,
                                                const int* __restrict__ cols,
                                                const float* __restrict__ vals,
                                                int* __restrict__ next,
                                                int2* __restrict__ cvp) {
    int e = blockIdx.x * 256 + threadIdx.x;
    if (e >= NEDGES) return;
    const int slot = atomicAdd(&next[rows[e]], 1);
    int2 p;
    p.x = cols[e];
    p.y = __builtin_bit_cast(int, vals[e]);
    cvp[slot] = p;
}

// ---------------------------------------------------------------------------
// Gather SpMM, bf16 X. One 64-lane wave per row, 4 cols/lane, 2-edge unroll.
// FUSE: in-place h = relu(acc + h) written bf16. Else: write fp32 out.
// ---------------------------------------------------------------------------
template <bool FUSE>
__global__ __launch_bounds__(256) void spmm_bf16(const int* __restrict__ row_ptr,
                                                 const int2* __restrict__ cvp,
                                                 const unsigned short* __restrict__ X,
                                                 unsigned short* __restrict__ Ybf,
                                                 float* __restrict__ Yf) {
    const int wid  = (blockIdx.x * 256 + threadIdx.x) >> 6;
    const int lane = threadIdx.x & 63;
    if (wid >= N_TOTAL) return;
    const int beg = row_ptr[wid], end = row_ptr[wid + 1];

    float a0 = 0.f, a1 = 0.f, a2 = 0.f, a3 = 0.f;
    int e = beg;
    for (; e + 1 < end; e += 2) {
        const int2 p0 = cvp[e], p1 = cvp[e + 1];
        const float v0 = __builtin_bit_cast(float, p0.y);
        const float v1 = __builtin_bit_cast(float, p1.y);
        const ushort4v x0 = *(const ushort4v*)(X + (size_t)p0.x * HID + lane * 4);
        const ushort4v x1 = *(const ushort4v*)(X + (size_t)p1.x * HID + lane * 4);
        a0 = fmaf(v0, bf2f(x0[0]), a0); a1 = fmaf(v0, bf2f(x0[1]), a1);
        a2 = fmaf(v0, bf2f(x0[2]), a2); a3 = fmaf(v0, bf2f(x0[3]), a3);
        a0 = fmaf(v1, bf2f(x1[0]), a0); a1 = fmaf(v1, bf2f(x1[1]), a1);
        a2 = fmaf(v1, bf2f(x1[2]), a2); a3 = fmaf(v1, bf2f(x1[3]), a3);
    }
    if (e < end) {
        const int2 p0 = cvp[e];
        const float v0 = __builtin_bit_cast(float, p0.y);
        const ushort4v x0 = *(const ushort4v*)(X + (size_t)p0.x * HID + lane * 4);
        a0 = fmaf(v0, bf2f(x0[0]), a0); a1 = fmaf(v0, bf2f(x0[1]), a1);
        a2 = fmaf(v0, bf2f(x0[2]), a2); a3 = fmaf(v0, bf2f(x0[3]), a3);
    }

    if (FUSE) {
        unsigned short* yp = Ybf + (size_t)wid * HID + lane * 4;
        const ushort4v rv = *(const ushort4v*)yp;
        a0 = fmaxf(a0 + bf2f(rv[0]), 0.f);
        a1 = fmaxf(a1 + bf2f(rv[1]), 0.f);
        a2 = fmaxf(a2 + bf2f(rv[2]), 0.f);
        a3 = fmaxf(a3 + bf2f(rv[3]), 0.f);
        ushort4v o; o[0] = f2bf(a0); o[1] = f2bf(a1); o[2] = f2bf(a2); o[3] = f2bf(a3);
        *(ushort4v*)yp = o;
    } else {
        f32x4 o = {a0, a1, a2, a3};
        *(f32x4*)(Yf + (size_t)wid * HID + lane * 4) = o;
    }
}

extern "C" void kernel_launch(void* const* d_in, const int* in_sizes, int n_in,
                              void* d_out, int out_size, void* d_ws, size_t ws_size,
                              hipStream_t stream) {
    const float* user_feat = (const float*)d_in[0];
    const float* item_feat = (const float*)d_in[1];
    const int*   edge_rows = (const int*)d_in[2];
    const int*   edge_cols = (const int*)d_in[3];
    const float* edge_vals = (const float*)d_in[4];
    const float* W0    = (const float*)d_in[5];
    const float* b0    = (const float*)d_in[6];
    const float* Wres0 = (const float*)d_in[7];
    const float* W1    = (const float*)d_in[8];
    const float* b1    = (const float*)d_in[9];
    float* out = (float*)d_out;

    char* ws = (char*)d_ws;
    auto take = [&](size_t bytes) { char* p = ws; ws += (bytes + 255) & ~(size_t)255; return p; };
    unsigned short* x      = (unsigned short*)take((size_t)M_PAD * HID * 2);
    unsigned short* h      = (unsigned short*)take((size_t)M_PAD * HID * 2);
    unsigned short* feats  = (unsigned short*)take((size_t)M_PAD * IN_DIM * 2);
    unsigned short* Wcat_t = (unsigned short*)take(512 * IN_DIM * 2);
    unsigned short* W1_t   = (unsigned short*)take(HID * HID * 2);
    int*   row_ptr = (int*)take((N_TOTAL + 1) * 4);
    int*   cnt     = (int*)take(N_TOTAL * 4);
    int*   nxt     = (int*)take(N_TOTAL * 4);
    int*   bsums   = (int*)take(128 * 4);
    int2*  cvp     = (int2*)take((size_t)NEDGES * 8);

    const dim3 blk(256);
    const int nscan = (N_TOTAL + SCAN_B - 1) / SCAN_B;

    // ---- Prep (bf16 casts) ----
    prep_feats<<<(N_TOTAL * IN_DIM / 8 + 255) / 256, blk, 0, stream>>>(user_feat, item_feat, feats);
    prep_weights<<<(512 * IN_DIM + HID * HID) / 256, blk, 0, stream>>>(W0, Wres0, W1, Wcat_t, W1_t);

    // ---- CSR build ----
    hipMemsetAsync(cnt, 0, N_TOTAL * 4, stream);
    edge_histogram<<<(NEDGES + 255) / 256, blk, 0, stream>>>(edge_rows, cnt);
    scan_blocks<<<nscan, SCAN_B, 0, stream>>>(cnt, row_ptr, bsums);
    scan_sums<<<1, 128, 0, stream>>>(bsums, nscan);
    scan_apply<<<nscan, SCAN_B, 0, stream>>>(row_ptr, bsums, nxt);
    csr_fill<<<(NEDGES + 255) / 256, blk, 0, stream>>>(edge_rows, edge_cols, edge_vals,
                                                       nxt, cvp);

    // ---- Layer 0: x = A@W0+b0 (gy=0), h = A@Wres0 (gy=1) ----
    mfma_gemm3<IN_DIM, 1><<<dim3(M_PAD / 64, 2), blk, 0, stream>>>(feats, Wcat_t, b0, x, h);

    // ---- h = relu(spmm(x) + h) in place ----
    const int spmm_blocks = (N_TOTAL * 64 + 255) / 256;
    spmm_bf16<true><<<spmm_blocks, blk, 0, stream>>>(row_ptr, cvp, x, h, nullptr);

    // ---- Layer 1: x2 = h@W1 + b1 ----
    mfma_gemm3<HID, 0><<<dim3(M_PAD / 64, 1), blk, 0, stream>>>(h, W1_t, b1, x, nullptr);

    // ---- out = spmm(x2), fp32 ----
    spmm_bf16<false><<<spmm_blocks, blk, 0, stream>>>(row_ptr, cvp, x, nullptr, out);
}

// Round 8
// 421.994 us; speedup vs baseline: 1.2315x; 1.2315x over previous
//
#include <hip/hip_runtime.h>

#define N_USERS 40000
#define N_ITEMS 60000
#define N_TOTAL 100000
#define M_PAD   100032   // rows padded to multiple of 64
#define NEDGES  600000
#define IN_DIM  128
#define HID     256

typedef short  bf16x8 __attribute__((ext_vector_type(8)));
typedef float  f32x4  __attribute__((ext_vector_type(4)));
typedef unsigned short ushort4v __attribute__((ext_vector_type(4)));
typedef unsigned short ushort8v __attribute__((ext_vector_type(8)));

__device__ __forceinline__ unsigned short f2bf(float f) {   // RNE fp32->bf16
    unsigned u = __builtin_bit_cast(unsigned, f);
    unsigned r = (u + 0x7FFFu + ((u >> 16) & 1u)) >> 16;
    return (unsigned short)r;
}
__device__ __forceinline__ float bf2f(unsigned short b) {
    unsigned u = ((unsigned)b) << 16;
    return __builtin_bit_cast(float, u);
}

__device__ __forceinline__ void gload_lds16(const void* g, void* l) {
    __builtin_amdgcn_global_load_lds(
        (const __attribute__((address_space(1))) unsigned int*)g,
        (__attribute__((address_space(3))) unsigned int*)l, 16, 0, 0);
}

// ---------------------------------------------------------------------------
// Prep: feats fp32 -> bf16 (concat user+item)
// ---------------------------------------------------------------------------
__global__ __launch_bounds__(256) void prep_feats(const float* __restrict__ uf,
                                                  const float* __restrict__ itf,
                                                  unsigned short* __restrict__ outp) {
    const long i8 = (long)(blockIdx.x * 256 + threadIdx.x) * 8;
    if (i8 >= (long)N_TOTAL * IN_DIM) return;
    const long uend = (long)N_USERS * IN_DIM;
    const float4* src = (i8 < uend) ? (const float4*)(uf + i8)
                                    : (const float4*)(itf + (i8 - uend));
    float4 a = src[0], b = src[1];
    ushort8v o;
    o[0] = f2bf(a.x); o[1] = f2bf(a.y); o[2] = f2bf(a.z); o[3] = f2bf(a.w);
    o[4] = f2bf(b.x); o[5] = f2bf(b.y); o[6] = f2bf(b.z); o[7] = f2bf(b.w);
    *(ushort8v*)(outp + i8) = o;
}

// ---------------------------------------------------------------------------
// Prep weights: Wcat2_t[n][k] (n-major, K=256): k<128 -> W0[k][n], else
// Wres0[k-128][n].  W1_t[n][k] = W1[k][n].  (both 256x256 bf16)
// ---------------------------------------------------------------------------
__global__ __launch_bounds__(256) void prep_weights(const float* __restrict__ W0,
                                                    const float* __restrict__ Wres0,
                                                    const float* __restrict__ W1,
                                                    unsigned short* __restrict__ Wcat2_t,
                                                    unsigned short* __restrict__ W1_t) {
    const int id = blockIdx.x * 256 + threadIdx.x;
    if (id < HID * HID) {
        const int n = id >> 8, k = id & 255;
        const float v = (k < IN_DIM) ? W0[(size_t)k * HID + n]
                                     : Wres0[(size_t)(k - IN_DIM) * HID + n];
        Wcat2_t[id] = f2bf(v);
    } else {
        const int id2 = id - HID * HID;
        const int n = id2 >> 8, k = id2 & 255;
        W1_t[id2] = f2bf(W1[(size_t)k * HID + n]);
    }
}

// ---------------------------------------------------------------------------
// MFMA GEMM v4: C[M,256] = A[M,256] @ Bt[n][k]^T (+epilogue), bf16 out.
// Block 64x256, 4 waves 2x2 (wave tile 32x128). A staged once (XOR-swizzled
// source, linear dest). B double-buffered in 32-K LDS chunks, ONE barrier per
// K-step. Epilogue through LDS bounce -> coalesced 16B stores (64 sh/thread).
// DUAL: A row = [A0[r] (k<128) | A1[r] (k>=128)], each 128-wide bf16.
// EPI=1: v = relu(acc + d[r]*bias[c]).  EPI=0: v = acc + bias[c].
// ---------------------------------------------------------------------------
template <int EPI, bool DUAL>
__global__ __launch_bounds__(256) void mfma_gemm4(const unsigned short* __restrict__ A0,
                                                  const unsigned short* __restrict__ A1,
                                                  const unsigned short* __restrict__ Bt,
                                                  const float* __restrict__ bias,
                                                  const float* __restrict__ dscale,
                                                  unsigned short* __restrict__ outp) {
    __shared__ unsigned short As[64 * 256];      // 32 KB
    __shared__ unsigned short Bs[2][256 * 32];   // 2 x 16 KB

    const int t  = threadIdx.x;
    const int w  = t >> 6, l = t & 63;
    const int fr = l & 15, fb = l >> 4;
    const int wr = w >> 1, wc = w & 1;
    const int m0 = blockIdx.x * 64;

    // ---- stage A (64 rows x 512 B); source pre-swizzled, dest linear ----
    #pragma unroll
    for (int i = 0; i < 8; ++i) {
        const int L   = (i * 256 + t) * 16;            // linear LDS byte
        const int row = L >> 9;
        const int W   = L & 511;
        const int U   = W ^ ((row & 7) << 4);          // swizzled in-row byte
        const char* src;
        if (DUAL) {
            src = (U < 256) ? (const char*)A0 + (size_t)(m0 + row) * 256 + U
                            : (const char*)A1 + (size_t)(m0 + row) * 256 + (U - 256);
        } else {
            src = (const char*)A0 + (size_t)(m0 + row) * 512 + U;
        }
        gload_lds16(src, (char*)As + L);
    }
    // ---- stage B chunk 0 ----
    #pragma unroll
    for (int i = 0; i < 4; ++i) {
        const int L = (i * 256 + t) * 16;
        const int n = L >> 6;
        const int q = (L >> 4) & 3;
        gload_lds16((const char*)Bt + (size_t)n * 512 + q * 16, (char*)Bs[0] + L);
    }
    __syncthreads();

    f32x4 acc[2][8] = {};
    for (int kt = 0; kt < 8; ++kt) {
        if (kt < 7) {   // issue next B chunk BEFORE compute (2-phase pipeline)
            #pragma unroll
            for (int i = 0; i < 4; ++i) {
                const int L = (i * 256 + t) * 16;
                const int n = L >> 6;
                const int q = (L >> 4) & 3;
                gload_lds16((const char*)Bt + (size_t)n * 512 + (kt + 1) * 64 + q * 16,
                            (char*)Bs[(kt + 1) & 1] + L);
            }
        }
        bf16x8 af[2];
        #pragma unroll
        for (int rb = 0; rb < 2; ++rb) {
            const int row = wr * 32 + rb * 16 + fr;
            const int Sa  = (row * 512 + kt * 64 + fb * 16) ^ ((fr & 7) << 4);
            af[rb] = *(const bf16x8*)((const char*)As + Sa);
        }
        const char* bs_base = (const char*)Bs[kt & 1];
        #pragma unroll
        for (int nt = 0; nt < 8; ++nt) {
            const int Sb = (wc * 128 + nt * 16 + fr) * 64 + fb * 16;
            const bf16x8 bfr = *(const bf16x8*)(bs_base + Sb);
            acc[0][nt] = __builtin_amdgcn_mfma_f32_16x16x32_bf16(af[0], bfr, acc[0][nt], 0, 0, 0);
            acc[1][nt] = __builtin_amdgcn_mfma_f32_16x16x32_bf16(af[1], bfr, acc[1][nt], 0, 0, 0);
        }
        __syncthreads();   // drains async stage + guards dbuf swap
    }

    // ---- epilogue: acc -> LDS (bf16) -> coalesced 16B stores ----
    unsigned short* Hb = As;   // reuse 32 KB: [64 rows][256 cols] bf16
    #pragma unroll
    for (int rb = 0; rb < 2; ++rb) {
        #pragma unroll
        for (int j = 0; j < 4; ++j) {
            const int rl = wr * 32 + rb * 16 + fb * 4 + j;
            const float ds = (EPI == 1) ? dscale[m0 + rl] : 0.f;
            #pragma unroll
            for (int nt = 0; nt < 8; ++nt) {
                const int col = wc * 128 + nt * 16 + fr;
                float v = acc[rb][nt][j];
                if (EPI == 1) v = fmaxf(v + ds * bias[col], 0.f);
                else          v = v + bias[col];
                Hb[rl * 256 + col] = f2bf(v);
            }
        }
    }
    __syncthreads();
    const int rowl = t >> 2;                       // 0..63
    const int cb   = (t & 3) * 64;                 // 64-elem chunk per thread
    unsigned short* gp = outp + (size_t)(m0 + rowl) * HID + cb;
    #pragma unroll
    for (int i = 0; i < 8; ++i)                    // 8 x 8 shorts = full 64
        *(ushort8v*)(gp + i * 8) = *(const ushort8v*)(Hb + rowl * 256 + cb + i * 8);
}

// ---------------------------------------------------------------------------
// CSR build: histogram -> exclusive scan -> fill (col,val packed as int2)
// ---------------------------------------------------------------------------
__global__ __launch_bounds__(256) void edge_histogram(const int* __restrict__ rows,
                                                      int* __restrict__ cnt) {
    int e = blockIdx.x * 256 + threadIdx.x;
    if (e < NEDGES) atomicAdd(&cnt[rows[e]], 1);
}

#define SCAN_B 1024
__global__ __launch_bounds__(SCAN_B) void scan_blocks(const int* __restrict__ cnt,
                                                      int* __restrict__ row_ptr,
                                                      int* __restrict__ bsums) {
    __shared__ int s[SCAN_B];
    const int gid = blockIdx.x * SCAN_B + threadIdx.x;
    const int v = (gid < N_TOTAL) ? cnt[gid] : 0;
    s[threadIdx.x] = v;
    __syncthreads();
    for (int off = 1; off < SCAN_B; off <<= 1) {
        int tv = (threadIdx.x >= off) ? s[threadIdx.x - off] : 0;
        __syncthreads();
        s[threadIdx.x] += tv;
        __syncthreads();
    }
    if (gid < N_TOTAL) row_ptr[gid] = s[threadIdx.x] - v;
    if (threadIdx.x == SCAN_B - 1) bsums[blockIdx.x] = s[threadIdx.x];
}

__global__ __launch_bounds__(128) void scan_sums(int* __restrict__ bsums, int nb) {
    __shared__ int s[128];
    const int v = (threadIdx.x < nb) ? bsums[threadIdx.x] : 0;
    s[threadIdx.x] = v;
    __syncthreads();
    for (int off = 1; off < 128; off <<= 1) {
        int tv = (threadIdx.x >= off) ? s[threadIdx.x - off] : 0;
        __syncthreads();
        s[threadIdx.x] += tv;
        __syncthreads();
    }
    if (threadIdx.x < nb) bsums[threadIdx.x] = s[threadIdx.x] - v;
}

__global__ __launch_bounds__(SCAN_B) void scan_apply(int* __restrict__ row_ptr,
                                                     const int* __restrict__ bsums,
                                                     int* __restrict__ next) {
    const int gid = blockIdx.x * SCAN_B + threadIdx.x;
    if (gid < N_TOTAL) {
        const int p = row_ptr[gid] + bsums[blockIdx.x];
        row_ptr[gid] = p;
        next[gid] = p;
    }
    if (gid == 0) row_ptr[N_TOTAL] = NEDGES;
}

__global__ __launch_bounds__(256) void csr_fill(const int* __restrict__ rows,
                                                const int* __restrict__ cols,
                                                const float* __restrict__ vals,
                                                int* __restrict__ next,
                                                int2* __restrict__ cvp) {
    int e = blockIdx.x * 256 + threadIdx.x;
    if (e >= NEDGES) return;
    const int slot = atomicAdd(&next[rows[e]], 1);
    int2 p;
    p.x = cols[e];
    p.y = __builtin_bit_cast(int, vals[e]);
    cvp[slot] = p;
}

// ---------------------------------------------------------------------------
// spmm1: g[r,:] = sum val*feats[col,:] (128-wide, 2 bf16/lane), d[r] = sum val.
// One wave per row.
// ---------------------------------------------------------------------------
__global__ __launch_bounds__(256) void spmm_feat(const int* __restrict__ row_ptr,
                                                 const int2* __restrict__ cvp,
                                                 const unsigned short* __restrict__ F,
                                                 unsigned short* __restrict__ G,
                                                 float* __restrict__ D) {
    const int wid  = (blockIdx.x * 256 + threadIdx.x) >> 6;
    const int lane = threadIdx.x & 63;
    if (wid >= N_TOTAL) return;
    const int beg = row_ptr[wid], end = row_ptr[wid + 1];

    float a0 = 0.f, a1 = 0.f, ds = 0.f;
    int e = beg;
    for (; e + 1 < end; e += 2) {
        const int2 p0 = cvp[e], p1 = cvp[e + 1];
        const float v0 = __builtin_bit_cast(float, p0.y);
        const float v1 = __builtin_bit_cast(float, p1.y);
        ds += v0 + v1;
        const unsigned x0 = *(const unsigned*)(F + (size_t)p0.x * IN_DIM + lane * 2);
        const unsigned x1 = *(const unsigned*)(F + (size_t)p1.x * IN_DIM + lane * 2);
        a0 = fmaf(v0, bf2f((unsigned short)(x0 & 0xFFFF)), a0);
        a1 = fmaf(v0, bf2f((unsigned short)(x0 >> 16)),   a1);
        a0 = fmaf(v1, bf2f((unsigned short)(x1 & 0xFFFF)), a0);
        a1 = fmaf(v1, bf2f((unsigned short)(x1 >> 16)),   a1);
    }
    if (e < end) {
        const int2 p0 = cvp[e];
        const float v0 = __builtin_bit_cast(float, p0.y);
        ds += v0;
        const unsigned x0 = *(const unsigned*)(F + (size_t)p0.x * IN_DIM + lane * 2);
        a0 = fmaf(v0, bf2f((unsigned short)(x0 & 0xFFFF)), a0);
        a1 = fmaf(v0, bf2f((unsigned short)(x0 >> 16)),   a1);
    }
    const unsigned ov = (unsigned)f2bf(a0) | ((unsigned)f2bf(a1) << 16);
    *(unsigned*)(G + (size_t)wid * IN_DIM + lane * 2) = ov;
    if (lane == 0) D[wid] = ds;
}

// ---------------------------------------------------------------------------
// spmm2: out[r,:] = sum val*X[col,:] (256-wide bf16 gather, fp32 out)
// ---------------------------------------------------------------------------
__global__ __launch_bounds__(256) void spmm_out(const int* __restrict__ row_ptr,
                                                const int2* __restrict__ cvp,
                                                const unsigned short* __restrict__ X,
                                                float* __restrict__ Yf) {
    const int wid  = (blockIdx.x * 256 + threadIdx.x) >> 6;
    const int lane = threadIdx.x & 63;
    if (wid >= N_TOTAL) return;
    const int beg = row_ptr[wid], end = row_ptr[wid + 1];

    float a0 = 0.f, a1 = 0.f, a2 = 0.f, a3 = 0.f;
    int e = beg;
    for (; e + 1 < end; e += 2) {
        const int2 p0 = cvp[e], p1 = cvp[e + 1];
        const float v0 = __builtin_bit_cast(float, p0.y);
        const float v1 = __builtin_bit_cast(float, p1.y);
        const ushort4v x0 = *(const ushort4v*)(X + (size_t)p0.x * HID + lane * 4);
        const ushort4v x1 = *(const ushort4v*)(X + (size_t)p1.x * HID + lane * 4);
        a0 = fmaf(v0, bf2f(x0[0]), a0); a1 = fmaf(v0, bf2f(x0[1]), a1);
        a2 = fmaf(v0, bf2f(x0[2]), a2); a3 = fmaf(v0, bf2f(x0[3]), a3);
        a0 = fmaf(v1, bf2f(x1[0]), a0); a1 = fmaf(v1, bf2f(x1[1]), a1);
        a2 = fmaf(v1, bf2f(x1[2]), a2); a3 = fmaf(v1, bf2f(x1[3]), a3);
    }
    if (e < end) {
        const int2 p0 = cvp[e];
        const float v0 = __builtin_bit_cast(float, p0.y);
        const ushort4v x0 = *(const ushort4v*)(X + (size_t)p0.x * HID + lane * 4);
        a0 = fmaf(v0, bf2f(x0[0]), a0); a1 = fmaf(v0, bf2f(x0[1]), a1);
        a2 = fmaf(v0, bf2f(x0[2]), a2); a3 = fmaf(v0, bf2f(x0[3]), a3);
    }
    f32x4 o = {a0, a1, a2, a3};
    *(f32x4*)(Yf + (size_t)wid * HID + lane * 4) = o;
}

extern "C" void kernel_launch(void* const* d_in, const int* in_sizes, int n_in,
                              void* d_out, int out_size, void* d_ws, size_t ws_size,
                              hipStream_t stream) {
    const float* user_feat = (const float*)d_in[0];
    const float* item_feat = (const float*)d_in[1];
    const int*   edge_rows = (const int*)d_in[2];
    const int*   edge_cols = (const int*)d_in[3];
    const float* edge_vals = (const float*)d_in[4];
    const float* W0    = (const float*)d_in[5];
    const float* b0    = (const float*)d_in[6];
    const float* Wres0 = (const float*)d_in[7];
    const float* W1    = (const float*)d_in[8];
    const float* b1    = (const float*)d_in[9];
    float* out = (float*)d_out;

    char* ws = (char*)d_ws;
    auto take = [&](size_t bytes) { char* p = ws; ws += (bytes + 255) & ~(size_t)255; return p; };
    unsigned short* feats   = (unsigned short*)take((size_t)M_PAD * IN_DIM * 2); // 25.6 MB
    unsigned short* g       = (unsigned short*)take((size_t)M_PAD * IN_DIM * 2); // 25.6 MB
    unsigned short* h       = (unsigned short*)take((size_t)M_PAD * HID * 2);    // 51.2 MB
    unsigned short* x2      = (unsigned short*)take((size_t)M_PAD * HID * 2);    // 51.2 MB
    float*          d       = (float*)take((size_t)M_PAD * 4);                   // 0.4 MB
    unsigned short* Wcat2_t = (unsigned short*)take(HID * HID * 2);
    unsigned short* W1_t    = (unsigned short*)take(HID * HID * 2);
    int*   row_ptr = (int*)take((N_TOTAL + 1) * 4);
    int*   cnt     = (int*)take(N_TOTAL * 4);
    int*   nxt     = (int*)take(N_TOTAL * 4);
    int*   bsums   = (int*)take(128 * 4);
    int2*  cvp     = (int2*)take((size_t)NEDGES * 8);

    const dim3 blk(256);
    const int nscan = (N_TOTAL + SCAN_B - 1) / SCAN_B;

    // ---- Prep (bf16 casts) ----
    prep_feats<<<(N_TOTAL * IN_DIM / 8 + 255) / 256, blk, 0, stream>>>(user_feat, item_feat, feats);
    prep_weights<<<(2 * HID * HID) / 256, blk, 0, stream>>>(W0, Wres0, W1, Wcat2_t, W1_t);

    // ---- CSR build ----
    hipMemsetAsync(cnt, 0, N_TOTAL * 4, stream);
    edge_histogram<<<(NEDGES + 255) / 256, blk, 0, stream>>>(edge_rows, cnt);
    scan_blocks<<<nscan, SCAN_B, 0, stream>>>(cnt, row_ptr, bsums);
    scan_sums<<<1, 128, 0, stream>>>(bsums, nscan);
    scan_apply<<<nscan, SCAN_B, 0, stream>>>(row_ptr, bsums, nxt);
    csr_fill<<<(NEDGES + 255) / 256, blk, 0, stream>>>(edge_rows, edge_cols, edge_vals,
                                                       nxt, cvp);

    const int spmm_blocks = (N_TOTAL * 64 + 255) / 256;

    // ---- g = spmm(feats), d = row-wise edge-weight sums ----
    spmm_feat<<<spmm_blocks, blk, 0, stream>>>(row_ptr, cvp, feats, g, d);

    // ---- h = relu([g|feats] @ [W0;Wres0] + d*b0) ----
    mfma_gemm4<1, true><<<M_PAD / 64, blk, 0, stream>>>(g, feats, Wcat2_t, b0, d, h);

    // ---- x2 = h @ W1 + b1 ----
    mfma_gemm4<0, false><<<M_PAD / 64, blk, 0, stream>>>(h, nullptr, W1_t, b1, nullptr, x2);

    // ---- out = spmm(x2), fp32 ----
    spmm_out<<<spmm_blocks, blk, 0, stream>>>(row_ptr, cvp, x2, out);
}